// Round 1
// baseline (571.812 us; speedup 1.0000x reference)
//
#include <hip/hip_runtime.h>

#define B_   4
#define N_   2048
#define C_   1024
#define H_   16
#define HKV_ 4
#define DH_  64
#define M_   (B_*N_)        // 8192 tokens
#define KSEL 1433           // max(1, int(2048*0.7)) = 1433

typedef unsigned short u16;
typedef short v8s __attribute__((ext_vector_type(8)));   // 8 bf16 (4 VGPR)
typedef float v4f __attribute__((ext_vector_type(4)));   // mfma accum

typedef __attribute__((address_space(1))) const void gconst_t;
typedef __attribute__((address_space(3))) void lds_t;

__device__ __forceinline__ u16 f2bf(float f) {
    union { float f; unsigned u; } v; v.f = f;
    unsigned u = v.u;
    return (u16)((u + 0x7fffu + ((u >> 16) & 1u)) >> 16);
}
__device__ __forceinline__ float bf2f(u16 b) {
    union { unsigned u; float f; } v; v.u = ((unsigned)b) << 16;
    return v.f;
}
__device__ __forceinline__ void gload_lds16(const void* g, void* l) {
    __builtin_amdgcn_global_load_lds((gconst_t*)g, (lds_t*)l, 16, 0, 0);
}

// ---------------- weight transpose: w[K][Nc] f32 -> wt[Nc][K] bf16 ----------------
__global__ void wtrans_kernel(const float* __restrict__ w, u16* __restrict__ wt,
                              int K, int Nc) {
    __shared__ float tile[32][33];
    int n0 = blockIdx.x * 32, k0 = blockIdx.y * 32;
    int tx = threadIdx.x, ty = threadIdx.y;              // block (32,8)
    #pragma unroll
    for (int i = 0; i < 32; i += 8)
        tile[ty + i][tx] = w[(size_t)(k0 + ty + i) * Nc + n0 + tx];
    __syncthreads();
    #pragma unroll
    for (int i = 0; i < 32; i += 8)
        wt[(size_t)(n0 + ty + i) * K + k0 + tx] = f2bf(tile[tx][ty + i]);
}

// ---------------- router: gate = sigmoid(x @ rw + rb), fp64 accumulation ----------------
__global__ void router_kernel(const float* __restrict__ x, const float* __restrict__ rw,
                              const float* __restrict__ rb, float* __restrict__ gate) {
    int wid = threadIdx.x >> 6, lane = threadIdx.x & 63;
    int t = blockIdx.x * 4 + wid;                        // token 0..8191
    const float4* xr  = (const float4*)(x + (size_t)t * C_);
    const float4* wr4 = (const float4*)rw;
    double acc = 0.0;
    #pragma unroll
    for (int i = 0; i < 4; i++) {
        float4 a = xr[i * 64 + lane];
        float4 w = wr4[i * 64 + lane];
        acc += (double)a.x * w.x + (double)a.y * w.y
             + (double)a.z * w.z + (double)a.w * w.w;
    }
    for (int off = 32; off > 0; off >>= 1) acc += __shfl_xor(acc, off);
    if (lane == 0) {
        double z = acc + (double)rb[0];
        gate[t] = (float)(1.0 / (1.0 + exp(-z)));
    }
}

// ---------------- top-k per batch: bitonic sort (val desc, idx asc), gm = gate*mask ----------------
__global__ void __launch_bounds__(1024) topk_kernel(const float* __restrict__ gate,
                                                    float* __restrict__ gm) {
    __shared__ float sv[N_];
    __shared__ int   si[N_];
    int b = blockIdx.x, tid = threadIdx.x;
    for (int j = tid; j < N_; j += 1024) { sv[j] = gate[b * N_ + j]; si[j] = j; }
    for (int size = 2; size <= N_; size <<= 1) {
        for (int stride = size >> 1; stride > 0; stride >>= 1) {
            __syncthreads();
            int lo = ((tid / stride) * (stride << 1)) + (tid % stride);
            int hi = lo + stride;
            bool desc = ((lo & size) == 0);
            float va = sv[lo], vb = sv[hi];
            int ia = si[lo], ib = si[hi];
            bool before = (va > vb) || (va == vb && ia < ib);  // a ranks before b
            if (before != desc) { sv[lo] = vb; sv[hi] = va; si[lo] = ib; si[hi] = ia; }
        }
    }
    __syncthreads();
    for (int j = tid; j < N_; j += 1024)
        gm[b * N_ + si[j]] = (j < KSEL) ? sv[j] : 0.0f;
}

// ---------------- xgm = bf16(x * gm) ----------------
__global__ void xgm_kernel(const float* __restrict__ x, const float* __restrict__ gm,
                           u16* __restrict__ xg) {
    size_t i = (size_t)blockIdx.x * blockDim.x + threadIdx.x;  // chunk of 8 elems
    int row = (int)(i >> 7);                                   // 128 chunks per row
    float g = gm[row];
    const float4* xp = (const float4*)(x + i * 8);
    float4 a = xp[0], b = xp[1];
    uint4 o;
    o.x = f2bf(a.x * g) | ((unsigned)f2bf(a.y * g) << 16);
    o.y = f2bf(a.z * g) | ((unsigned)f2bf(a.w * g) << 16);
    o.z = f2bf(b.x * g) | ((unsigned)f2bf(b.y * g) << 16);
    o.w = f2bf(b.z * g) | ((unsigned)f2bf(b.w * g) << 16);
    ((uint4*)xg)[i] = o;
}

// ---------------- GEMM: C[M][Nn] = A[M][K]bf16 @ BT[Nn][K]bf16^T + bias ----------------
// m97 structure: 128x128 tile, BK=32, 4 waves each 64x64 (4x4 frags of 16x16x32)
template <bool STORE_BF16>
__global__ void __launch_bounds__(256) gemm_bt(const u16* __restrict__ A,
                                               const u16* __restrict__ BT,
                                               const float* __restrict__ bias,
                                               void* __restrict__ Cout,
                                               int Mm, int Nn, int Kk) {
    __shared__ u16 As[128 * 32];
    __shared__ u16 Bs[128 * 32];
    int m0 = blockIdx.x * 128, n0 = blockIdx.y * 128;
    int tid = threadIdx.x, wid = tid >> 6, lane = tid & 63;
    int wr = wid >> 1, wc = wid & 1;
    v4f acc[4][4] = {};

    for (int k0 = 0; k0 < Kk; k0 += 32) {
        // stage tiles via global_load_lds (wave-uniform LDS base + lane*16)
        int ebase = wid * 1024;                 // elements (2KB per wave)
        #pragma unroll
        for (int c = 0; c < 2; c++) {
            int e = ebase + c * 512 + lane * 8; // this lane's linear elem offset
            int row = e >> 5, col = e & 31;
            gload_lds16(A  + (size_t)(m0 + row) * Kk + k0 + col, &As[ebase + c * 512]);
            gload_lds16(BT + (size_t)(n0 + row) * Kk + k0 + col, &Bs[ebase + c * 512]);
        }
        __syncthreads();
        int rA = wr * 64 + (lane & 15);
        int rB = wc * 64 + (lane & 15);
        int kc = (lane >> 4) * 8;
        v8s af[4], bf[4];
        #pragma unroll
        for (int m = 0; m < 4; m++) af[m] = *(const v8s*)&As[(rA + m * 16) * 32 + kc];
        #pragma unroll
        for (int n = 0; n < 4; n++) bf[n] = *(const v8s*)&Bs[(rB + n * 16) * 32 + kc];
        #pragma unroll
        for (int m = 0; m < 4; m++)
            #pragma unroll
            for (int n = 0; n < 4; n++)
                acc[m][n] = __builtin_amdgcn_mfma_f32_16x16x32_bf16(af[m], bf[n], acc[m][n], 0, 0, 0);
        __syncthreads();
    }
    // epilogue: C row = m0+wr*64+m*16+(lane>>4)*4+r, col = n0+wc*64+n*16+(lane&15)
    int cr0 = m0 + wr * 64 + (lane >> 4) * 4;
    int cc0 = n0 + wc * 64 + (lane & 15);
    #pragma unroll
    for (int m = 0; m < 4; m++)
        #pragma unroll
        for (int n = 0; n < 4; n++) {
            int gr = cr0 + m * 16, gc = cc0 + n * 16;
            float bval = bias[gc];
            #pragma unroll
            for (int r = 0; r < 4; r++) {
                float v = acc[m][n][r] + bval;
                if (STORE_BF16) ((u16*)Cout)[(size_t)(gr + r) * Nn + gc] = f2bf(v);
                else            ((float*)Cout)[(size_t)(gr + r) * Nn + gc] = v;
            }
        }
}

// ---------------- flash attention: block = (b, h, 128 q-rows), 4 waves x 32 rows ----------------
__global__ void __launch_bounds__(256) attn_kernel(const u16* __restrict__ Q,
                                                   const u16* __restrict__ Kb,
                                                   const u16* __restrict__ Vb,
                                                   u16* __restrict__ O) {
    int bx = blockIdx.x;
    int qt = bx & 15;            // N/128 = 16 q-tiles
    int h  = (bx >> 4) & 15;
    int b  = bx >> 8;
    int hkv = h >> 2;            // jnp.repeat: head h -> kv head h/4
    int n0 = qt * 128;
    int tid = threadIdx.x, wid = tid >> 6, lane = tid & 63;
    int l15 = lane & 15, lg = lane >> 4;

    __shared__ u16 Qs[128][72];   // +8 pad: conflict-free ds_read_b128
    __shared__ u16 Ks[64][72];
    __shared__ u16 VTs[64][72];   // V transposed: [dh][key]
    __shared__ u16 Ps[128][72];   // P round-trip, per-wave 32-row regions

    // stage Q (pre-scaled by 1/sqrt(DH)=0.125 — exact exponent shift)
    const size_t qbase = ((size_t)b * N_ + n0) * C_ + (size_t)h * DH_;
    #pragma unroll
    for (int i = 0; i < 4; i++) {
        int chunk = i * 256 + tid;                 // 128 rows * 8 chunks
        int r = chunk >> 3, cb = (chunk & 7) * 8;
        v8s v = *(const v8s*)(Q + qbase + (size_t)r * C_ + cb);
        u16 tmp[8];
        #pragma unroll
        for (int e = 0; e < 8; e++) tmp[e] = f2bf(bf2f((u16)v[e]) * 0.125f);
        *(v8s*)&Qs[r][cb] = *(v8s*)tmp;
    }
    __syncthreads();

    // Q fragments (held in regs for whole K loop): A[i=row][k=dh]
    v8s qf[2][2];
    #pragma unroll
    for (int fr = 0; fr < 2; fr++)
        #pragma unroll
        for (int kh = 0; kh < 2; kh++)
            qf[fr][kh] = *(const v8s*)&Qs[wid * 32 + fr * 16 + l15][kh * 32 + lg * 8];

    v4f o_acc[2][4] = {};
    float m_run[2][4], l_run[2][4];
    #pragma unroll
    for (int fr = 0; fr < 2; fr++)
        #pragma unroll
        for (int r = 0; r < 4; r++) { m_run[fr][r] = -1e30f; l_run[fr][r] = 0.0f; }

    const size_t kvbase = (size_t)b * N_ * (HKV_ * DH_) + (size_t)hkv * DH_;

    for (int kt = 0; kt < N_ / 64; kt++) {
        int key0 = kt * 64;
        // stage K row-major and V transposed
        #pragma unroll
        for (int i = 0; i < 2; i++) {
            int chunk = i * 256 + tid;             // 64 rows * 8 chunks
            int j = chunk >> 3, cb = (chunk & 7) * 8;
            const u16* src = Kb + kvbase + (size_t)(key0 + j) * (HKV_ * DH_) + cb;
            *(v8s*)&Ks[j][cb] = *(const v8s*)src;
            v8s vv = *(const v8s*)(Vb + kvbase + (size_t)(key0 + j) * (HKV_ * DH_) + cb);
            #pragma unroll
            for (int e = 0; e < 8; e++) VTs[cb + e][j] = (u16)vv[e];
        }
        __syncthreads();

        // S = (Q/8) @ K^T  : B[k=dh][j=key] -> frag = Ks[key][dh] contiguous
        v4f s[2][4];
        #pragma unroll
        for (int fc = 0; fc < 4; fc++) {
            v8s bk0 = *(const v8s*)&Ks[fc * 16 + l15][lg * 8];
            v8s bk1 = *(const v8s*)&Ks[fc * 16 + l15][32 + lg * 8];
            #pragma unroll
            for (int fr = 0; fr < 2; fr++) {
                v4f z = {};
                z = __builtin_amdgcn_mfma_f32_16x16x32_bf16(qf[fr][0], bk0, z, 0, 0, 0);
                z = __builtin_amdgcn_mfma_f32_16x16x32_bf16(qf[fr][1], bk1, z, 0, 0, 0);
                s[fr][fc] = z;
            }
        }

        // online softmax; row = fr*16 + lg*4 + r, cols = fc*16 + l15
        #pragma unroll
        for (int fr = 0; fr < 2; fr++) {
            #pragma unroll
            for (int r = 0; r < 4; r++) {
                float m4 = fmaxf(fmaxf(s[fr][0][r], s[fr][1][r]),
                                 fmaxf(s[fr][2][r], s[fr][3][r]));
                #pragma unroll
                for (int d = 1; d < 16; d <<= 1) m4 = fmaxf(m4, __shfl_xor(m4, d));
                float mn = fmaxf(m_run[fr][r], m4);
                float alpha = __expf(m_run[fr][r] - mn);
                m_run[fr][r] = mn;
                float rs = 0.0f;
                #pragma unroll
                for (int fc = 0; fc < 4; fc++) {
                    float p = __expf(s[fr][fc][r] - mn);
                    s[fr][fc][r] = p;
                    rs += p;
                }
                #pragma unroll
                for (int d = 1; d < 16; d <<= 1) rs += __shfl_xor(rs, d);
                l_run[fr][r] = l_run[fr][r] * alpha + rs;
                #pragma unroll
                for (int fd = 0; fd < 4; fd++) o_acc[fr][fd][r] *= alpha;
            }
            // P -> LDS (C-layout scatter), re-read below as A-fragments
            int prow = wid * 32 + fr * 16 + lg * 4;
            #pragma unroll
            for (int r = 0; r < 4; r++)
                #pragma unroll
                for (int fc = 0; fc < 4; fc++)
                    Ps[prow + r][fc * 16 + l15] = f2bf(s[fr][fc][r]);
        }

        // O += P @ V : A = P[qrow][key], B = V[key][dh] via VTs[dh][key]
        #pragma unroll
        for (int kq = 0; kq < 2; kq++) {
            v8s pv[2], vf[4];
            #pragma unroll
            for (int fr = 0; fr < 2; fr++)
                pv[fr] = *(const v8s*)&Ps[wid * 32 + fr * 16 + l15][kq * 32 + lg * 8];
            #pragma unroll
            for (int fd = 0; fd < 4; fd++)
                vf[fd] = *(const v8s*)&VTs[fd * 16 + l15][kq * 32 + lg * 8];
            #pragma unroll
            for (int fr = 0; fr < 2; fr++)
                #pragma unroll
                for (int fd = 0; fd < 4; fd++)
                    o_acc[fr][fd] = __builtin_amdgcn_mfma_f32_16x16x32_bf16(pv[fr], vf[fd], o_acc[fr][fd], 0, 0, 0);
        }
        __syncthreads();
    }

    // epilogue: O[b, n0+row, h*64 + fd*16 + l15] = o_acc / l
    #pragma unroll
    for (int fr = 0; fr < 2; fr++) {
        int row0 = wid * 32 + fr * 16 + lg * 4;
        #pragma unroll
        for (int r = 0; r < 4; r++) {
            float inv = 1.0f / l_run[fr][r];
            size_t orow = ((size_t)b * N_ + n0 + row0 + r) * C_ + (size_t)h * DH_;
            #pragma unroll
            for (int fd = 0; fd < 4; fd++)
                O[orow + fd * 16 + l15] = f2bf(o_acc[fr][fd][r] * inv);
        }
    }
}

// ---------------- launch ----------------
extern "C" void kernel_launch(void* const* d_in, const int* in_sizes, int n_in,
                              void* d_out, int out_size, void* d_ws, size_t ws_size,
                              hipStream_t stream) {
    (void)in_sizes; (void)n_in; (void)out_size; (void)ws_size;
    const float* x  = (const float*)d_in[0];
    const float* rw = (const float*)d_in[1];
    const float* rb = (const float*)d_in[2];
    const float* wq = (const float*)d_in[3];
    const float* bq = (const float*)d_in[4];
    const float* wk = (const float*)d_in[5];
    const float* bk = (const float*)d_in[6];
    const float* wv = (const float*)d_in[7];
    const float* bv = (const float*)d_in[8];
    const float* wo = (const float*)d_in[9];
    const float* bo = (const float*)d_in[10];
    float* out = (float*)d_out;

    // workspace layout (~21 MB)
    char* ws = (char*)d_ws;
    size_t off = 0;
    auto alloc = [&](size_t bytes) {
        void* p = ws + off; off += (bytes + 255) & ~(size_t)255; return p;
    };
    u16*  wqT  = (u16*)alloc((size_t)C_ * C_ * 2);
    u16*  wkT  = (u16*)alloc((size_t)(HKV_ * DH_) * C_ * 2);
    u16*  wvT  = (u16*)alloc((size_t)(HKV_ * DH_) * C_ * 2);
    u16*  woT  = (u16*)alloc((size_t)C_ * C_ * 2);
    float* gate = (float*)alloc((size_t)M_ * 4);
    float* gm   = (float*)alloc((size_t)M_ * 4);
    u16*  xgm  = (u16*)alloc((size_t)M_ * C_ * 2);
    u16*  ob   = xgm;  // O reuses xgm (xgm dead after V projection)

    // park q/k/v bf16 in d_out (32 MB) — final GEMM overwrites it afterwards
    u16* qb = (u16*)d_out;                                    // 16 MB
    u16* kb = (u16*)((char*)d_out + (size_t)M_ * C_ * 2);     // 4 MB
    u16* vb = (u16*)((char*)kb + (size_t)M_ * (HKV_ * DH_) * 2); // 4 MB

    dim3 tb(32, 8);
    wtrans_kernel<<<dim3(C_ / 32, C_ / 32), tb, 0, stream>>>(wq, wqT, C_, C_);
    wtrans_kernel<<<dim3((HKV_ * DH_) / 32, C_ / 32), tb, 0, stream>>>(wk, wkT, C_, HKV_ * DH_);
    wtrans_kernel<<<dim3((HKV_ * DH_) / 32, C_ / 32), tb, 0, stream>>>(wv, wvT, C_, HKV_ * DH_);
    wtrans_kernel<<<dim3(C_ / 32, C_ / 32), tb, 0, stream>>>(wo, woT, C_, C_);

    router_kernel<<<M_ / 4, 256, 0, stream>>>(x, rw, rb, gate);
    topk_kernel<<<B_, 1024, 0, stream>>>(gate, gm);
    xgm_kernel<<<(M_ * C_ / 8) / 256, 256, 0, stream>>>(x, gm, xgm);

    gemm_bt<true><<<dim3(M_ / 128, C_ / 128), 256, 0, stream>>>(xgm, wqT, bq, qb, M_, C_, C_);
    gemm_bt<true><<<dim3(M_ / 128, (HKV_ * DH_) / 128), 256, 0, stream>>>(xgm, wkT, bk, kb, M_, HKV_ * DH_, C_);
    gemm_bt<true><<<dim3(M_ / 128, (HKV_ * DH_) / 128), 256, 0, stream>>>(xgm, wvT, bv, vb, M_, HKV_ * DH_, C_);

    attn_kernel<<<B_ * H_ * (N_ / 128), 256, 0, stream>>>(qb, kb, vb, ob);

    gemm_bt<false><<<dim3(M_ / 128, C_ / 128), 256, 0, stream>>>(ob, woT, bo, out, M_, C_, C_);
}

// Round 3
// 490.805 us; speedup vs baseline: 1.1650x; 1.1650x over previous
//
#include <hip/hip_runtime.h>

#define B_   4
#define N_   2048
#define C_   1024
#define H_   16
#define HKV_ 4
#define DH_  64
#define M_   (B_*N_)        // 8192 tokens
#define KSEL 1433           // max(1, int(2048*0.7)) = 1433
#define QKV_LD 1536         // fused q|k|v row stride

typedef unsigned short u16;
typedef short v8s __attribute__((ext_vector_type(8)));   // 8 bf16 (4 VGPR)
typedef float v4f __attribute__((ext_vector_type(4)));   // 16x16 mfma accum
typedef float v16f __attribute__((ext_vector_type(16))); // 32x32 mfma accum
typedef unsigned v4u __attribute__((ext_vector_type(4)));

typedef __attribute__((address_space(1))) const void gconst_t;
typedef __attribute__((address_space(3))) void lds_t;

__device__ __forceinline__ u16 f2bf(float f) {
    union { float f; unsigned u; } v; v.f = f;
    unsigned u = v.u;
    return (u16)((u + 0x7fffu + ((u >> 16) & 1u)) >> 16);
}
// packed f32x2 -> bf16x2 (round-nearest-even), T12 recipe: no builtin on gfx950
__device__ __forceinline__ unsigned pk2(float lo, float hi_) {
    unsigned r;
    asm("v_cvt_pk_bf16_f32 %0, %1, %2" : "=v"(r) : "v"(lo), "v"(hi_));
    return r;
}
__device__ __forceinline__ void gload_lds16(const void* g, void* l) {
    __builtin_amdgcn_global_load_lds((gconst_t*)g, (lds_t*)l, 16, 0, 0);
}

// ---------------- weight transpose: w[K][Nc] f32 -> wt[Nc][K] bf16 ----------------
__global__ void wtrans_kernel(const float* __restrict__ w, u16* __restrict__ wt,
                              int K, int Nc) {
    __shared__ float tile[32][33];
    int n0 = blockIdx.x * 32, k0 = blockIdx.y * 32;
    int tx = threadIdx.x, ty = threadIdx.y;              // block (32,8)
    #pragma unroll
    for (int i = 0; i < 32; i += 8)
        tile[ty + i][tx] = w[(size_t)(k0 + ty + i) * Nc + n0 + tx];
    __syncthreads();
    #pragma unroll
    for (int i = 0; i < 32; i += 8)
        wt[(size_t)(n0 + ty + i) * K + k0 + tx] = f2bf(tile[tx][ty + i]);
}

// ---------------- bias concat bq|bk|bv -> [1536] ----------------
__global__ void bcat_kernel(const float* __restrict__ bq, const float* __restrict__ bk,
                            const float* __restrict__ bv, float* __restrict__ o) {
    int t = blockIdx.x * 256 + threadIdx.x;
    float v;
    if (t < 1024) v = bq[t];
    else if (t < 1280) v = bk[t - 1024];
    else v = bv[t - 1280];
    o[t] = v;
}

// ---------------- router: gate = sigmoid(x @ rw + rb), fp64 accumulation ----------------
__global__ void router_kernel(const float* __restrict__ x, const float* __restrict__ rw,
                              const float* __restrict__ rb, float* __restrict__ gate) {
    int wid = threadIdx.x >> 6, lane = threadIdx.x & 63;
    int t = blockIdx.x * 4 + wid;                        // token 0..8191
    const float4* xr  = (const float4*)(x + (size_t)t * C_);
    const float4* wr4 = (const float4*)rw;
    double acc = 0.0;
    #pragma unroll
    for (int i = 0; i < 4; i++) {
        float4 a = xr[i * 64 + lane];
        float4 w = wr4[i * 64 + lane];
        acc += (double)a.x * w.x + (double)a.y * w.y
             + (double)a.z * w.z + (double)a.w * w.w;
    }
    for (int off = 32; off > 0; off >>= 1) acc += __shfl_xor(acc, off);
    if (lane == 0) {
        double z = acc + (double)rb[0];
        gate[t] = (float)(1.0 / (1.0 + exp(-z)));
    }
}

// ---------------- top-k per batch: bitonic sort (val desc, idx asc), gm = gate*mask ----------------
__global__ void __launch_bounds__(1024) topk_kernel(const float* __restrict__ gate,
                                                    float* __restrict__ gm) {
    __shared__ float sv[N_];
    __shared__ int   si[N_];
    int b = blockIdx.x, tid = threadIdx.x;
    for (int j = tid; j < N_; j += 1024) { sv[j] = gate[b * N_ + j]; si[j] = j; }
    for (int size = 2; size <= N_; size <<= 1) {
        for (int stride = size >> 1; stride > 0; stride >>= 1) {
            __syncthreads();
            int lo = ((tid / stride) * (stride << 1)) + (tid % stride);
            int hi = lo + stride;
            bool desc = ((lo & size) == 0);
            float va = sv[lo], vb = sv[hi];
            int ia = si[lo], ib = si[hi];
            bool before = (va > vb) || (va == vb && ia < ib);  // a ranks before b
            if (before != desc) { sv[lo] = vb; sv[hi] = va; si[lo] = ib; si[hi] = ia; }
        }
    }
    __syncthreads();
    for (int j = tid; j < N_; j += 1024)
        gm[b * N_ + si[j]] = (j < KSEL) ? sv[j] : 0.0f;
}

// ---------------- xgm = bf16(x * gm) ----------------
__global__ void xgm_kernel(const float* __restrict__ x, const float* __restrict__ gm,
                           u16* __restrict__ xg) {
    size_t i = (size_t)blockIdx.x * blockDim.x + threadIdx.x;  // chunk of 8 elems
    int row = (int)(i >> 7);                                   // 128 chunks per row
    float g = gm[row];
    const float4* xp = (const float4*)(x + i * 8);
    float4 a = xp[0], b = xp[1];
    uint4 o;
    o.x = f2bf(a.x * g) | ((unsigned)f2bf(a.y * g) << 16);
    o.y = f2bf(a.z * g) | ((unsigned)f2bf(a.w * g) << 16);
    o.z = f2bf(b.x * g) | ((unsigned)f2bf(b.y * g) << 16);
    o.w = f2bf(b.z * g) | ((unsigned)f2bf(b.w * g) << 16);
    ((uint4*)xg)[i] = o;
}

// ---------------- GEMM: C[M][Nn] = A[M][K]bf16 @ BT[Nn][K]bf16^T + bias ----------------
template <bool STORE_BF16>
__global__ void __launch_bounds__(256) gemm_bt(const u16* __restrict__ A,
                                               const u16* __restrict__ BT,
                                               const float* __restrict__ bias,
                                               void* __restrict__ Cout,
                                               int Mm, int Nn, int Kk) {
    __shared__ u16 As[128 * 32];
    __shared__ u16 Bs[128 * 32];
    int m0 = blockIdx.x * 128, n0 = blockIdx.y * 128;
    int tid = threadIdx.x, wid = tid >> 6, lane = tid & 63;
    int wr = wid >> 1, wc = wid & 1;
    v4f acc[4][4] = {};

    for (int k0 = 0; k0 < Kk; k0 += 32) {
        int ebase = wid * 1024;
        #pragma unroll
        for (int c = 0; c < 2; c++) {
            int e = ebase + c * 512 + lane * 8;
            int row = e >> 5, col = e & 31;
            gload_lds16(A  + (size_t)(m0 + row) * Kk + k0 + col, &As[ebase + c * 512]);
            gload_lds16(BT + (size_t)(n0 + row) * Kk + k0 + col, &Bs[ebase + c * 512]);
        }
        __syncthreads();
        int rA = wr * 64 + (lane & 15);
        int rB = wc * 64 + (lane & 15);
        int kc = (lane >> 4) * 8;
        v8s af[4], bf[4];
        #pragma unroll
        for (int m = 0; m < 4; m++) af[m] = *(const v8s*)&As[(rA + m * 16) * 32 + kc];
        #pragma unroll
        for (int n = 0; n < 4; n++) bf[n] = *(const v8s*)&Bs[(rB + n * 16) * 32 + kc];
        #pragma unroll
        for (int m = 0; m < 4; m++)
            #pragma unroll
            for (int n = 0; n < 4; n++)
                acc[m][n] = __builtin_amdgcn_mfma_f32_16x16x32_bf16(af[m], bf[n], acc[m][n], 0, 0, 0);
        __syncthreads();
    }
    int cr0 = m0 + wr * 64 + (lane >> 4) * 4;
    int cc0 = n0 + wc * 64 + (lane & 15);
    #pragma unroll
    for (int m = 0; m < 4; m++)
        #pragma unroll
        for (int n = 0; n < 4; n++) {
            int gr = cr0 + m * 16, gc = cc0 + n * 16;
            float bval = bias[gc];
            #pragma unroll
            for (int r = 0; r < 4; r++) {
                float v = acc[m][n][r] + bval;
                if (STORE_BF16) ((u16*)Cout)[(size_t)(gr + r) * Nn + gc] = f2bf(v);
                else            ((float*)Cout)[(size_t)(gr + r) * Nn + gc] = v;
            }
        }
}

// ---------------- flash attention, swapped-QK^T 32x32x16 structure ----------------
// grid 512: bx = qt*64 + h*4 + b  (h*4+b fast => 2MB K/V footprint per XCD L2)
// block 512 = 8 waves; wave owns 32 q-rows; KVBLK=64; in-register softmax
__global__ void __launch_bounds__(512, 4) attn2_kernel(const u16* __restrict__ QKV,
                                                       u16* __restrict__ Ob) {
    int bx = blockIdx.x;
    int b  = bx & 3;
    int h  = (bx >> 2) & 15;
    int qt = bx >> 6;
    int hkv = h >> 2;
    int tok0 = qt * 256;
    int tid = threadIdx.x, wid = tid >> 6, lane = tid & 63;
    int l31 = lane & 31, hi = lane >> 5;

    __shared__ u16 smem[256 * 66];
    u16 (*Klds)[66]  = (u16(*)[66])smem;               // [64 key][64 dh], stride 66
    u16 (*VTlds)[66] = (u16(*)[66])(smem + 64 * 66);   // [64 dh][64 key], stride 66
    u16 (*Olds)[66]  = (u16(*)[66])smem;               // epilogue reuse [256 q][64 dh]

    // Q fragments (B-operand of swapped QK): lane holds Q[q=l31][dh window]
    int qrow = tok0 + wid * 32 + l31;
    const u16* qptr = QKV + ((size_t)b * N_ + qrow) * QKV_LD + h * 64;
    v8s qb[4];
    #pragma unroll
    for (int kk = 0; kk < 4; kk++)
        qb[kk] = *(const v8s*)(qptr + kk * 16 + hi * 8);

    v16f o0 = {}, o1 = {};                  // O^T accum: dh rows [0..31], [32..63]
    float m_run = -INFINITY, l_run = 0.0f;  // per q-row (both half-lanes agree)

    const u16* kvbase = QKV + (size_t)b * N_ * QKV_LD + 1024 + hkv * DH_;
    int sr = tid >> 3, sc = (tid & 7) * 8;  // staging: key row, col base

    for (int kt = 0; kt < N_ / 64; kt++) {
        const u16* kvp = kvbase + (size_t)(kt * 64 + sr) * QKV_LD + sc;
        v8s kvec = *(const v8s*)kvp;
        v8s vvec = *(const v8s*)(kvp + 256);            // V = K offset + 256 cols
        *(v8s*)&Klds[sr][sc] = kvec;
        #pragma unroll
        for (int e = 0; e < 8; e++) VTlds[sc + e][sr] = (u16)vvec[e];
        __syncthreads();

        #pragma unroll
        for (int s = 0; s < 2; s++) {                   // 32-key subtile
            // S^T[key][q] = K_sub @ Q^T  (raw scores; scale folded into exp)
            v16f c = {};
            #pragma unroll
            for (int kk = 0; kk < 4; kk++) {
                v8s ak = *(const v8s*)&Klds[s * 32 + l31][kk * 16 + hi * 8];
                c = __builtin_amdgcn_mfma_f32_32x32x16_bf16(ak, qb[kk], c, 0, 0, 0);
            }
            // in-lane max over 16 keys, then cross-half combine
            float t0 = fmaxf(fmaxf(c[0], c[1]),  fmaxf(c[2], c[3]));
            float t1 = fmaxf(fmaxf(c[4], c[5]),  fmaxf(c[6], c[7]));
            float t2 = fmaxf(fmaxf(c[8], c[9]),  fmaxf(c[10], c[11]));
            float t3 = fmaxf(fmaxf(c[12], c[13]), fmaxf(c[14], c[15]));
            float tmax = fmaxf(fmaxf(t0, t1), fmaxf(t2, t3));
            tmax = fmaxf(tmax, __shfl_xor(tmax, 32));
            // defer-max: raw-score THR 64 == 8 in e-units (P bounded by e^8)
            if (!__all(tmax <= m_run + 64.0f)) {
                float mnew = fmaxf(m_run, tmax);
                float al = __expf((m_run - mnew) * 0.125f);
                l_run *= al;
                o0 *= al; o1 *= al;
                m_run = mnew;
            }
            float m8 = m_run * 0.125f;
            float p[16];
            #pragma unroll
            for (int r = 0; r < 16; r++)
                p[r] = __expf(__builtin_fmaf(c[r], 0.125f, -m8));
            float s0 = (p[0] + p[1]) + (p[2] + p[3]);
            float s1 = (p[4] + p[5]) + (p[6] + p[7]);
            float s2 = (p[8] + p[9]) + (p[10] + p[11]);
            float s3 = (p[12] + p[13]) + (p[14] + p[15]);
            float ps = (s0 + s1) + (s2 + s3);
            ps += __shfl_xor(ps, 32);
            l_run += ps;
            // pack P -> bf16 words; key(j-word) = {4h+2j', ...} per C-layout
            unsigned w[8];
            #pragma unroll
            for (int j = 0; j < 8; j++) w[j] = pk2(p[2 * j], p[2 * j + 1]);
            // build PV B-fragments via cross-half swap, then PV MFMA
            #pragma unroll
            for (int kk = 0; kk < 2; kk++) {
                unsigned a0 = w[kk * 4 + 0], a1 = w[kk * 4 + 1];
                unsigned b0 = w[kk * 4 + 2], b1 = w[kk * 4 + 3];
                unsigned xa0 = __shfl_xor(a0, 32), xa1 = __shfl_xor(a1, 32);
                unsigned xb0 = __shfl_xor(b0, 32), xb1 = __shfl_xor(b1, 32);
                v4u pw;
                pw.x = hi ? xb0 : a0;   // keys 16kk+8h+0,1
                pw.y = hi ? xb1 : a1;   // keys 16kk+8h+2,3
                pw.z = hi ? b0  : xa0;  // keys 16kk+8h+4,5
                pw.w = hi ? b1  : xa1;  // keys 16kk+8h+6,7
                v8s pb = __builtin_bit_cast(v8s, pw);
                v8s av0 = *(const v8s*)&VTlds[l31][s * 32 + kk * 16 + hi * 8];
                v8s av1 = *(const v8s*)&VTlds[32 + l31][s * 32 + kk * 16 + hi * 8];
                o0 = __builtin_amdgcn_mfma_f32_32x32x16_bf16(av0, pb, o0, 0, 0, 0);
                o1 = __builtin_amdgcn_mfma_f32_32x32x16_bf16(av1, pb, o1, 0, 0, 0);
            }
        }
        __syncthreads();
    }

    // epilogue: O^T regs -> Olds[q][dh] (transpose via LDS), then coalesced store
    float inv = 1.0f / l_run;
    #pragma unroll
    for (int rr = 0; rr < 4; rr++) {
        int dh0 = rr * 8 + hi * 4;                      // rows (r&3)+8rr+4hi
        unsigned w0 = pk2(o0[rr * 4 + 0] * inv, o0[rr * 4 + 1] * inv);
        unsigned w1 = pk2(o0[rr * 4 + 2] * inv, o0[rr * 4 + 3] * inv);
        unsigned w2 = pk2(o1[rr * 4 + 0] * inv, o1[rr * 4 + 1] * inv);
        unsigned w3 = pk2(o1[rr * 4 + 2] * inv, o1[rr * 4 + 3] * inv);
        u16* dp = &Olds[wid * 32 + l31][dh0];
        *(unsigned*)dp = w0;
        *(unsigned*)(dp + 2) = w1;
        u16* dp2 = &Olds[wid * 32 + l31][32 + dh0];
        *(unsigned*)dp2 = w2;
        *(unsigned*)(dp2 + 2) = w3;
    }
    __syncthreads();
    #pragma unroll
    for (int i = 0; i < 4; i++) {
        int idx = i * 512 + tid;
        int r = idx >> 3, cb = (idx & 7) * 8;
        *(v8s*)(Ob + ((size_t)(b * N_ + tok0 + r)) * C_ + h * DH_ + cb) =
            *(const v8s*)&Olds[r][cb];
    }
}

// ---------------- launch ----------------
extern "C" void kernel_launch(void* const* d_in, const int* in_sizes, int n_in,
                              void* d_out, int out_size, void* d_ws, size_t ws_size,
                              hipStream_t stream) {
    (void)in_sizes; (void)n_in; (void)out_size; (void)ws_size;
    const float* x  = (const float*)d_in[0];
    const float* rw = (const float*)d_in[1];
    const float* rb = (const float*)d_in[2];
    const float* wq = (const float*)d_in[3];
    const float* bq = (const float*)d_in[4];
    const float* wk = (const float*)d_in[5];
    const float* bk = (const float*)d_in[6];
    const float* wv = (const float*)d_in[7];
    const float* bv = (const float*)d_in[8];
    const float* wo = (const float*)d_in[9];
    const float* bo = (const float*)d_in[10];
    float* out = (float*)d_out;

    char* ws = (char*)d_ws;
    size_t off = 0;
    auto alloc = [&](size_t bytes) {
        void* p = ws + off; off += (bytes + 255) & ~(size_t)255; return p;
    };
    u16*  wqkvT = (u16*)alloc((size_t)QKV_LD * C_ * 2);   // 3 MB  [1536][1024]
    u16*  woT   = (u16*)alloc((size_t)C_ * C_ * 2);       // 2 MB
    float* bqkv = (float*)alloc((size_t)QKV_LD * 4);
    float* gate = (float*)alloc((size_t)M_ * 4);
    float* gm   = (float*)alloc((size_t)M_ * 4);
    u16*  xgm  = (u16*)alloc((size_t)M_ * C_ * 2);        // 16 MB
    u16*  ob   = xgm;   // attn output reuses xgm (dead after QKV GEMM)

    u16* qkv = (u16*)d_out;   // [8192][1536] bf16 = 24 MB parked in d_out

    dim3 tb(32, 8);
    wtrans_kernel<<<dim3(32, 32), tb, 0, stream>>>(wq, wqkvT, C_, C_);
    wtrans_kernel<<<dim3(8, 32),  tb, 0, stream>>>(wk, wqkvT + (size_t)1024 * C_, C_, HKV_ * DH_);
    wtrans_kernel<<<dim3(8, 32),  tb, 0, stream>>>(wv, wqkvT + (size_t)1280 * C_, C_, HKV_ * DH_);
    wtrans_kernel<<<dim3(32, 32), tb, 0, stream>>>(wo, woT, C_, C_);
    bcat_kernel<<<6, 256, 0, stream>>>(bq, bk, bv, bqkv);

    router_kernel<<<M_ / 4, 256, 0, stream>>>(x, rw, rb, gate);
    topk_kernel<<<B_, 1024, 0, stream>>>(gate, gm);
    xgm_kernel<<<(M_ * C_ / 8) / 256, 256, 0, stream>>>(x, gm, xgm);

    gemm_bt<true><<<dim3(M_ / 128, QKV_LD / 128), 256, 0, stream>>>(xgm, wqkvT, bqkv, qkv, M_, QKV_LD, C_);

    attn2_kernel<<<B_ * H_ * (N_ / 256), 512, 0, stream>>>(qkv, ob);

    gemm_bt<false><<<dim3(M_ / 128, C_ / 128), 256, 0, stream>>>(ob, woT, bo, out, M_, C_, C_);
}

// Round 6
// 459.482 us; speedup vs baseline: 1.2445x; 1.0682x over previous
//
#include <hip/hip_runtime.h>

#define B_   4
#define N_   2048
#define C_   1024
#define H_   16
#define HKV_ 4
#define DH_  64
#define M_   (B_*N_)        // 8192 tokens
#define KSEL 1433           // max(1, int(2048*0.7)) = 1433
#define QKV_LD 1536         // fused q|k|v row stride

typedef unsigned short u16;
typedef short v8s __attribute__((ext_vector_type(8)));   // 8 bf16 (4 VGPR)
typedef float v4f __attribute__((ext_vector_type(4)));   // 16x16 mfma accum
typedef float v16f __attribute__((ext_vector_type(16))); // 32x32 mfma accum
typedef unsigned v4u __attribute__((ext_vector_type(4)));

typedef __attribute__((address_space(1))) const void gconst_t;
typedef __attribute__((address_space(3))) void lds_t;

__device__ __forceinline__ u16 f2bf(float f) {
    union { float f; unsigned u; } v; v.f = f;
    unsigned u = v.u;
    return (u16)((u + 0x7fffu + ((u >> 16) & 1u)) >> 16);
}
// packed f32x2 -> bf16x2 (round-nearest-even), T12 recipe: no builtin on gfx950
__device__ __forceinline__ unsigned pk2(float lo, float hi_) {
    unsigned r;
    asm("v_cvt_pk_bf16_f32 %0, %1, %2" : "=v"(r) : "v"(lo), "v"(hi_));
    return r;
}
// cross-half swap: a' = [a.lo | b.lo], b' = [a.hi | b.hi]
__device__ __forceinline__ void pswap(unsigned &a, unsigned &b, int hi) {
#if __has_builtin(__builtin_amdgcn_permlane32_swap)
    (void)hi;
    auto r = __builtin_amdgcn_permlane32_swap(a, b, false, false);
    a = r[0]; b = r[1];
#else
    unsigned xa = __shfl_xor((int)a, 32), xb = __shfl_xor((int)b, 32);
    unsigned na = hi ? xb : a, nb = hi ? b : xa;
    a = na; b = nb;
#endif
}
__device__ __forceinline__ void pswapf(float &a, float &b, int hi) {
    unsigned ua = __float_as_uint(a), ub = __float_as_uint(b);
    pswap(ua, ub, hi);
    a = __uint_as_float(ua); b = __uint_as_float(ub);
}
__device__ __forceinline__ void gload_lds16(const void* g, void* l) {
    __builtin_amdgcn_global_load_lds((gconst_t*)g, (lds_t*)l, 16, 0, 0);
}

// ---------------- weight transpose: w[K][Nc] f32 -> wt[Nc][K] bf16 ----------------
__global__ void wtrans_kernel(const float* __restrict__ w, u16* __restrict__ wt,
                              int K, int Nc) {
    __shared__ float tile[32][33];
    int n0 = blockIdx.x * 32, k0 = blockIdx.y * 32;
    int tx = threadIdx.x, ty = threadIdx.y;              // block (32,8)
    #pragma unroll
    for (int i = 0; i < 32; i += 8)
        tile[ty + i][tx] = w[(size_t)(k0 + ty + i) * Nc + n0 + tx];
    __syncthreads();
    #pragma unroll
    for (int i = 0; i < 32; i += 8)
        wt[(size_t)(n0 + ty + i) * K + k0 + tx] = f2bf(tile[tx][ty + i]);
}

// ---------------- bias concat bq|bk|bv -> [1536] ----------------
__global__ void bcat_kernel(const float* __restrict__ bq, const float* __restrict__ bk,
                            const float* __restrict__ bv, float* __restrict__ o) {
    int t = blockIdx.x * 256 + threadIdx.x;
    float v;
    if (t < 1024) v = bq[t];
    else if (t < 1280) v = bk[t - 1024];
    else v = bv[t - 1280];
    o[t] = v;
}

// ---------------- router: gate = sigmoid(x @ rw + rb), fp64 accumulation ----------------
__global__ void router_kernel(const float* __restrict__ x, const float* __restrict__ rw,
                              const float* __restrict__ rb, float* __restrict__ gate) {
    int wid = threadIdx.x >> 6, lane = threadIdx.x & 63;
    int t = blockIdx.x * 4 + wid;                        // token 0..8191
    const float4* xr  = (const float4*)(x + (size_t)t * C_);
    const float4* wr4 = (const float4*)rw;
    double acc = 0.0;
    #pragma unroll
    for (int i = 0; i < 4; i++) {
        float4 a = xr[i * 64 + lane];
        float4 w = wr4[i * 64 + lane];
        acc += (double)a.x * w.x + (double)a.y * w.y
             + (double)a.z * w.z + (double)a.w * w.w;
    }
    for (int off = 32; off > 0; off >>= 1) acc += __shfl_xor(acc, off);
    if (lane == 0) {
        double z = acc + (double)rb[0];
        gate[t] = (float)(1.0 / (1.0 + exp(-z)));
    }
}

// ---------------- top-k per batch: bitonic sort (val desc, idx asc), gm = gate*mask ----------------
__global__ void __launch_bounds__(1024) topk_kernel(const float* __restrict__ gate,
                                                    float* __restrict__ gm) {
    __shared__ float sv[N_];
    __shared__ int   si[N_];
    int b = blockIdx.x, tid = threadIdx.x;
    for (int j = tid; j < N_; j += 1024) { sv[j] = gate[b * N_ + j]; si[j] = j; }
    for (int size = 2; size <= N_; size <<= 1) {
        for (int stride = size >> 1; stride > 0; stride >>= 1) {
            __syncthreads();
            int lo = ((tid / stride) * (stride << 1)) + (tid % stride);
            int hi = lo + stride;
            bool desc = ((lo & size) == 0);
            float va = sv[lo], vb = sv[hi];
            int ia = si[lo], ib = si[hi];
            bool before = (va > vb) || (va == vb && ia < ib);  // a ranks before b
            if (before != desc) { sv[lo] = vb; sv[hi] = va; si[lo] = ib; si[hi] = ia; }
        }
    }
    __syncthreads();
    for (int j = tid; j < N_; j += 1024)
        gm[b * N_ + si[j]] = (j < KSEL) ? sv[j] : 0.0f;
}

// ---------------- xgm = bf16(x * gm) ----------------
__global__ void xgm_kernel(const float* __restrict__ x, const float* __restrict__ gm,
                           u16* __restrict__ xg) {
    size_t i = (size_t)blockIdx.x * blockDim.x + threadIdx.x;  // chunk of 8 elems
    int row = (int)(i >> 7);                                   // 128 chunks per row
    float g = gm[row];
    const float4* xp = (const float4*)(x + i * 8);
    float4 a = xp[0], b = xp[1];
    uint4 o;
    o.x = f2bf(a.x * g) | ((unsigned)f2bf(a.y * g) << 16);
    o.y = f2bf(a.z * g) | ((unsigned)f2bf(a.w * g) << 16);
    o.z = f2bf(b.x * g) | ((unsigned)f2bf(b.y * g) << 16);
    o.w = f2bf(b.z * g) | ((unsigned)f2bf(b.w * g) << 16);
    ((uint4*)xg)[i] = o;
}

// ---------------- GEMM: C[M][Nn] = A[M][K]bf16 @ BT[Nn][K]bf16^T + bias ----------------
template <bool STORE_BF16>
__global__ void __launch_bounds__(256) gemm_bt(const u16* __restrict__ A,
                                               const u16* __restrict__ BT,
                                               const float* __restrict__ bias,
                                               void* __restrict__ Cout,
                                               int Mm, int Nn, int Kk) {
    __shared__ u16 As[128 * 32];
    __shared__ u16 Bs[128 * 32];
    int m0 = blockIdx.x * 128, n0 = blockIdx.y * 128;
    int tid = threadIdx.x, wid = tid >> 6, lane = tid & 63;
    int wr = wid >> 1, wc = wid & 1;
    v4f acc[4][4] = {};

    for (int k0 = 0; k0 < Kk; k0 += 32) {
        int ebase = wid * 1024;
        #pragma unroll
        for (int c = 0; c < 2; c++) {
            int e = ebase + c * 512 + lane * 8;
            int row = e >> 5, col = e & 31;
            gload_lds16(A  + (size_t)(m0 + row) * Kk + k0 + col, &As[ebase + c * 512]);
            gload_lds16(BT + (size_t)(n0 + row) * Kk + k0 + col, &Bs[ebase + c * 512]);
        }
        __syncthreads();
        int rA = wr * 64 + (lane & 15);
        int rB = wc * 64 + (lane & 15);
        int kc = (lane >> 4) * 8;
        v8s af[4], bf[4];
        #pragma unroll
        for (int m = 0; m < 4; m++) af[m] = *(const v8s*)&As[(rA + m * 16) * 32 + kc];
        #pragma unroll
        for (int n = 0; n < 4; n++) bf[n] = *(const v8s*)&Bs[(rB + n * 16) * 32 + kc];
        #pragma unroll
        for (int m = 0; m < 4; m++)
            #pragma unroll
            for (int n = 0; n < 4; n++)
                acc[m][n] = __builtin_amdgcn_mfma_f32_16x16x32_bf16(af[m], bf[n], acc[m][n], 0, 0, 0);
        __syncthreads();
    }
    int cr0 = m0 + wr * 64 + (lane >> 4) * 4;
    int cc0 = n0 + wc * 64 + (lane & 15);
    #pragma unroll
    for (int m = 0; m < 4; m++)
        #pragma unroll
        for (int n = 0; n < 4; n++) {
            int gr = cr0 + m * 16, gc = cc0 + n * 16;
            float bval = bias[gc];
            #pragma unroll
            for (int r = 0; r < 4; r++) {
                float v = acc[m][n][r] + bval;
                if (STORE_BF16) ((u16*)Cout)[(size_t)(gr + r) * Nn + gc] = f2bf(v);
                else            ((float*)Cout)[(size_t)(gr + r) * Nn + gc] = v;
            }
        }
}

// ---------------- flash attention v3: swapped-QK^T 32x32x16, dbuf K/V, 1 barrier/iter ----------------
// grid 512: bx = qt*64 + h*4 + b; block 512 = 8 waves; wave owns 32 q-rows; KVBLK=64
__global__ void __launch_bounds__(512, 4) attn3_kernel(const u16* __restrict__ QKV,
                                                       u16* __restrict__ Ob) {
    int bx = blockIdx.x;
    int b  = bx & 3;
    int h  = (bx >> 2) & 15;
    int qt = bx >> 6;
    int hkv = h >> 2;
    int tok0 = qt * 256;
    int tid = threadIdx.x, wid = tid >> 6, lane = tid & 63;
    int l31 = lane & 31, hi = lane >> 5;

    // 33792 B total: 4 buffers of 64x66 u16 (K0,V0,K1,V1); epilogue overlays all
    __shared__ u16 smem[256 * 66];
    u16 (*K0)[66] = (u16(*)[66])(smem);
    u16 (*V0)[66] = (u16(*)[66])(smem + 4224);   // V^T: [dh][key]
    u16 (*K1)[66] = (u16(*)[66])(smem + 8448);
    u16 (*V1)[66] = (u16(*)[66])(smem + 12672);
    u16 (*Olds)[66] = (u16(*)[66])smem;          // epilogue reuse [256 q][64 dh]

    // Q fragments (B-operand of swapped QK): lane holds Q[q=l31][dh window]
    int qrow = tok0 + wid * 32 + l31;
    const u16* qptr = QKV + ((size_t)b * N_ + qrow) * QKV_LD + h * 64;
    v8s qb[4];
    #pragma unroll
    for (int kk = 0; kk < 4; kk++)
        qb[kk] = *(const v8s*)(qptr + kk * 16 + hi * 8);

    v16f o0 = {}, o1 = {};                  // O^T accum: dh rows [0..31], [32..63]
    float m_run = -INFINITY, l_run = 0.0f;  // per q-row (both half-lanes agree)

    const u16* kbase = QKV + (size_t)b * N_ * QKV_LD + 1024 + hkv * DH_;
    int sr = tid >> 3, sc = (tid & 7) * 8;  // staging: key row, col base

    // prologue: stage tile 0 into buf0
    v8s kst = *(const v8s*)(kbase + (size_t)sr * QKV_LD + sc);
    v8s vst = *(const v8s*)(kbase + (size_t)sr * QKV_LD + sc + 256);
    *(v8s*)&K0[sr][sc] = kst;
    #pragma unroll
    for (int e = 0; e < 8; e++) V0[sc + e][sr] = (u16)vst[e];
    __syncthreads();

    for (int kt = 0; kt < N_ / 64; kt++) {
        u16 (*Kr)[66] = (kt & 1) ? K1 : K0;
        u16 (*Vr)[66] = (kt & 1) ? V1 : V0;
        u16 (*Kw)[66] = (kt & 1) ? K0 : K1;
        u16 (*Vw)[66] = (kt & 1) ? V0 : V1;
        bool pf = (kt < N_ / 64 - 1);
        if (pf) {   // T14: issue next-tile loads now, write to LDS after compute
            const u16* nrow = kbase + (size_t)((kt + 1) * 64 + sr) * QKV_LD + sc;
            kst = *(const v8s*)nrow;
            vst = *(const v8s*)(nrow + 256);
        }

        #pragma unroll
        for (int s = 0; s < 2; s++) {                   // 32-key subtile
            // S^T[key][q] = K_sub @ Q^T  (raw scores; scale folded into exp)
            v16f c = {};
            __builtin_amdgcn_s_setprio(1);
            #pragma unroll
            for (int kk = 0; kk < 4; kk++) {
                v8s ak = *(const v8s*)&Kr[s * 32 + l31][kk * 16 + hi * 8];
                c = __builtin_amdgcn_mfma_f32_32x32x16_bf16(ak, qb[kk], c, 0, 0, 0);
            }
            __builtin_amdgcn_s_setprio(0);
            // in-lane max over 16 keys, then cross-half combine (pure VALU)
            float t0 = fmaxf(fmaxf(c[0], c[1]),  fmaxf(c[2], c[3]));
            float t1 = fmaxf(fmaxf(c[4], c[5]),  fmaxf(c[6], c[7]));
            float t2 = fmaxf(fmaxf(c[8], c[9]),  fmaxf(c[10], c[11]));
            float t3 = fmaxf(fmaxf(c[12], c[13]), fmaxf(c[14], c[15]));
            float tmax = fmaxf(fmaxf(t0, t1), fmaxf(t2, t3));
            { float ta = tmax, tb = tmax; pswapf(ta, tb, hi); tmax = fmaxf(ta, tb); }
            // defer-max: raw-score THR 64 == 8 in e-units (P bounded by e^8)
            if (!__all(tmax <= m_run + 64.0f)) {
                float mnew = fmaxf(m_run, tmax);
                float al = __expf((m_run - mnew) * 0.125f);
                l_run *= al;
                o0 *= al; o1 *= al;
                m_run = mnew;
            }
            float m8 = m_run * 0.125f;
            float p[16];
            #pragma unroll
            for (int r = 0; r < 16; r++)
                p[r] = __expf(__builtin_fmaf(c[r], 0.125f, -m8));
            float s0 = (p[0] + p[1]) + (p[2] + p[3]);
            float s1 = (p[4] + p[5]) + (p[6] + p[7]);
            float s2 = (p[8] + p[9]) + (p[10] + p[11]);
            float s3 = (p[12] + p[13]) + (p[14] + p[15]);
            float ps = (s0 + s1) + (s2 + s3);
            { float sa = ps, sb = ps; pswapf(sa, sb, hi); ps = sa + sb; }
            l_run += ps;
            // pack P -> bf16 words; build PV B-fragments via permlane32_swap
            unsigned w[8];
            #pragma unroll
            for (int j = 0; j < 8; j++) w[j] = pk2(p[2 * j], p[2 * j + 1]);
            #pragma unroll
            for (int kk = 0; kk < 2; kk++) {
                unsigned px = w[kk * 4 + 0], pz = w[kk * 4 + 2];
                unsigned py = w[kk * 4 + 1], pw_ = w[kk * 4 + 3];
                pswap(px, pz, hi);          // px=[a0.lo|b0.lo]  pz=[a0.hi|b0.hi]
                pswap(py, pw_, hi);
                v4u pv4; pv4.x = px; pv4.y = py; pv4.z = pz; pv4.w = pw_;
                v8s pb = __builtin_bit_cast(v8s, pv4);
                v8s av0 = *(const v8s*)&Vr[l31][s * 32 + kk * 16 + hi * 8];
                v8s av1 = *(const v8s*)&Vr[32 + l31][s * 32 + kk * 16 + hi * 8];
                __builtin_amdgcn_s_setprio(1);
                o0 = __builtin_amdgcn_mfma_f32_32x32x16_bf16(av0, pb, o0, 0, 0, 0);
                o1 = __builtin_amdgcn_mfma_f32_32x32x16_bf16(av1, pb, o1, 0, 0, 0);
                __builtin_amdgcn_s_setprio(0);
            }
        }

        if (pf) {   // write next tile into the other buffer (no barrier needed first)
            *(v8s*)&Kw[sr][sc] = kst;
            #pragma unroll
            for (int e = 0; e < 8; e++) Vw[sc + e][sr] = (u16)vst[e];
        }
        __syncthreads();
    }

    // epilogue: O^T regs -> Olds[q][dh] (transpose via LDS), then coalesced store
    float inv = 1.0f / l_run;
    #pragma unroll
    for (int rr = 0; rr < 4; rr++) {
        int dh0 = rr * 8 + hi * 4;                      // rows (r&3)+8rr+4hi
        unsigned w0 = pk2(o0[rr * 4 + 0] * inv, o0[rr * 4 + 1] * inv);
        unsigned w1 = pk2(o0[rr * 4 + 2] * inv, o0[rr * 4 + 3] * inv);
        unsigned w2 = pk2(o1[rr * 4 + 0] * inv, o1[rr * 4 + 1] * inv);
        unsigned w3 = pk2(o1[rr * 4 + 2] * inv, o1[rr * 4 + 3] * inv);
        u16* dp = &Olds[wid * 32 + l31][dh0];
        *(unsigned*)dp = w0;
        *(unsigned*)(dp + 2) = w1;
        u16* dp2 = &Olds[wid * 32 + l31][32 + dh0];
        *(unsigned*)dp2 = w2;
        *(unsigned*)(dp2 + 2) = w3;
    }
    __syncthreads();
    #pragma unroll
    for (int i = 0; i < 4; i++) {
        int idx = i * 512 + tid;
        int r = idx >> 3, cb = (idx & 7) * 8;
        *(v8s*)(Ob + ((size_t)(b * N_ + tok0 + r)) * C_ + h * DH_ + cb) =
            *(const v8s*)&Olds[r][cb];
    }
}

// ---------------- launch ----------------
extern "C" void kernel_launch(void* const* d_in, const int* in_sizes, int n_in,
                              void* d_out, int out_size, void* d_ws, size_t ws_size,
                              hipStream_t stream) {
    (void)in_sizes; (void)n_in; (void)out_size; (void)ws_size;
    const float* x  = (const float*)d_in[0];
    const float* rw = (const float*)d_in[1];
    const float* rb = (const float*)d_in[2];
    const float* wq = (const float*)d_in[3];
    const float* bq = (const float*)d_in[4];
    const float* wk = (const float*)d_in[5];
    const float* bk = (const float*)d_in[6];
    const float* wv = (const float*)d_in[7];
    const float* bv = (const float*)d_in[8];
    const float* wo = (const float*)d_in[9];
    const float* bo = (const float*)d_in[10];
    float* out = (float*)d_out;

    char* ws = (char*)d_ws;
    size_t off = 0;
    auto alloc = [&](size_t bytes) {
        void* p = ws + off; off += (bytes + 255) & ~(size_t)255; return p;
    };
    u16*  wqkvT = (u16*)alloc((size_t)QKV_LD * C_ * 2);   // 3 MB  [1536][1024]
    u16*  woT   = (u16*)alloc((size_t)C_ * C_ * 2);       // 2 MB
    float* bqkv = (float*)alloc((size_t)QKV_LD * 4);
    float* gate = (float*)alloc((size_t)M_ * 4);
    float* gm   = (float*)alloc((size_t)M_ * 4);
    u16*  xgm  = (u16*)alloc((size_t)M_ * C_ * 2);        // 16 MB
    u16*  ob   = xgm;   // attn output reuses xgm (dead after QKV GEMM)

    u16* qkv = (u16*)d_out;   // [8192][1536] bf16 = 24 MB parked in d_out

    dim3 tb(32, 8);
    wtrans_kernel<<<dim3(32, 32), tb, 0, stream>>>(wq, wqkvT, C_, C_);
    wtrans_kernel<<<dim3(8, 32),  tb, 0, stream>>>(wk, wqkvT + (size_t)1024 * C_, C_, HKV_ * DH_);
    wtrans_kernel<<<dim3(8, 32),  tb, 0, stream>>>(wv, wqkvT + (size_t)1280 * C_, C_, HKV_ * DH_);
    wtrans_kernel<<<dim3(32, 32), tb, 0, stream>>>(wo, woT, C_, C_);
    bcat_kernel<<<6, 256, 0, stream>>>(bq, bk, bv, bqkv);

    router_kernel<<<M_ / 4, 256, 0, stream>>>(x, rw, rb, gate);
    topk_kernel<<<B_, 1024, 0, stream>>>(gate, gm);
    xgm_kernel<<<(M_ * C_ / 8) / 256, 256, 0, stream>>>(x, gm, xgm);

    gemm_bt<true><<<dim3(M_ / 128, QKV_LD / 128), 256, 0, stream>>>(xgm, wqkvT, bqkv, qkv, M_, QKV_LD, C_);

    attn3_kernel<<<B_ * H_ * (N_ / 256), 512, 0, stream>>>(qkv, ob);

    gemm_bt<false><<<dim3(M_ / 128, C_ / 128), 256, 0, stream>>>(ob, woT, bo, out, M_, C_, C_);
}